// Round 5
// baseline (117.289 us; speedup 1.0000x reference)
//
#include <hip/hip_runtime.h>
#include <hip/hip_bf16.h>

#define BB 4
#define IN_DIM 8
#define OUT_DIM 64
#define N_WIN 64
#define N_SEQ 4096
#define N_REAL 6144

#define OG 8                       // output channels per block
#define TTILE 256                  // t positions per block (64 lanes x 4 consecutive t)
#define ZROWS (TTILE + N_WIN - 1)  // 319 rows incl. halo
#define RPAD 320                   // plane pitch (floats); 8 planes = 10240 B LDS

__global__ __launch_bounds__(64)
void astrf_fused(const float* __restrict__ x,
                 const float* __restrict__ w,
                 const float* __restrict__ bias,
                 const int* __restrict__ sidx,
                 float* __restrict__ out)
{
    __shared__ float zsh[IN_DIM * RPAD];   // [i][row], row = t' - (t0-63)

    const int tid = threadIdx.x;
    const int t0  = blockIdx.x * TTILE;
    const int o0  = blockIdx.y * OG;
    const int b   = blockIdx.z;

    // ---- zero the scatter timeline (float4 writes) ----
    {
        float4* zp = (float4*)zsh;
        #pragma unroll
        for (int k = 0; k < (IN_DIM * RPAD / 4) / 64; ++k)
            zp[k * 64 + tid] = make_float4(0.f, 0.f, 0.f, 0.f);
    }
    __syncthreads();

    // ---- scatter: scan all sources (coalesced idx loads, no dependent search) ----
    const int* idxb = sidx + b * N_SEQ;
    const int vlo = t0 - (N_WIN - 1);
    for (int k = tid; k < N_SEQ; k += 64) {
        int r = idxb[k] - vlo;
        if ((unsigned)r < (unsigned)ZROWS) {
            const float* xp = x + (size_t)b * IN_DIM * N_SEQ + k;
            #pragma unroll
            for (int i = 0; i < IN_DIM; ++i)
                zsh[i * RPAD + r] = xp[(size_t)i * N_SEQ];
        }
    }
    __syncthreads();

    // ---- dense correlation: lane owns t = t0 + 4*tid + c, c=0..3 ----
    float acc[OG][4];
    #pragma unroll
    for (int o = 0; o < OG; ++o)
        #pragma unroll
        for (int c = 0; c < 4; ++c) acc[o][c] = 0.f;

    const float* wb = w + (size_t)o0 * IN_DIM * N_WIN;  // w[o0+o][i][l]

    for (int lb = 0; lb < N_WIN; lb += 4) {
        #pragma unroll
        for (int i = 0; i < IN_DIM; ++i) {
            // wave-uniform weight loads -> scalar pipe (w[o][i][lb..lb+3])
            float wreg[OG][4];
            #pragma unroll
            for (int o = 0; o < OG; ++o) {
                const float4 wv = *(const float4*)&wb[((size_t)o * IN_DIM + i) * N_WIN + lb];
                wreg[o][0] = wv.x; wreg[o][1] = wv.y; wreg[o][2] = wv.z; wreg[o][3] = wv.w;
            }
            // aligned 8-float window: rows R..R+7, R = 4*tid + 60 - lb (16B aligned)
            const int base = i * RPAD + 4 * tid + (N_WIN - 4) - lb;
            const float4 za = *(const float4*)&zsh[base];
            const float4 zb = *(const float4*)&zsh[base + 4];
            const float zarr[8] = {za.x, za.y, za.z, za.w, zb.x, zb.y, zb.z, zb.w};

            // l = lb+dl needs rows (4tid+c) + 63 - l = base + (3-dl) + c
            #pragma unroll
            for (int dl = 0; dl < 4; ++dl) {
                #pragma unroll
                for (int c = 0; c < 4; ++c) {
                    const float zv = zarr[3 - dl + c];
                    #pragma unroll
                    for (int o = 0; o < OG; ++o)
                        acc[o][c] += wreg[o][dl] * zv;
                }
            }
        }
    }

    // ---- epilogue: bias + float4 store (lane writes 16B, wave covers 1KB) ----
    #pragma unroll
    for (int o = 0; o < OG; ++o) {
        const float bv = bias[o0 + o];
        float4 v = make_float4(acc[o][0] + bv, acc[o][1] + bv,
                               acc[o][2] + bv, acc[o][3] + bv);
        *(float4*)&out[((size_t)b * OUT_DIM + o0 + o) * N_REAL + t0 + 4 * tid] = v;
    }
}

extern "C" void kernel_launch(void* const* d_in, const int* in_sizes, int n_in,
                              void* d_out, int out_size, void* d_ws, size_t ws_size,
                              hipStream_t stream) {
    const float* px = nullptr; const float* pw = nullptr;
    const float* pb = nullptr; const int* ps = nullptr;

    for (int i = 0; i < n_in; ++i) {
        switch (in_sizes[i]) {
            case BB * IN_DIM * N_SEQ:        px = (const float*)d_in[i]; break; // 131072 x
            case OUT_DIM * IN_DIM * N_WIN:   pw = (const float*)d_in[i]; break; // 32768 weight
            case OUT_DIM:                    pb = (const float*)d_in[i]; break; // 64 bias
            case BB * N_SEQ:                 ps = (const int*)d_in[i];   break; // 16384 idx
            default: break;                                                      // nRealLen scalar
        }
    }
    if (!px || !pw || !pb || !ps) {  // fall back to dict order (shouldn't happen)
        px = (const float*)d_in[0]; pw = (const float*)d_in[1];
        pb = (const float*)d_in[2]; ps = (const int*)d_in[3];
    }

    float* out = (float*)d_out;
    dim3 grid(N_REAL / TTILE, OUT_DIM / OG, BB);  // 24 x 8 x 4 = 768 blocks
    astrf_fused<<<grid, dim3(64), 0, stream>>>(px, pw, pb, ps, out);
}